// Round 2
// baseline (2173.956 us; speedup 1.0000x reference)
//
#include <hip/hip_runtime.h>
#include <float.h>

#define N_ROWS 65536
#define K_CB   4096
#define D_DIM  256

#define RB 128   // rows per block (fast pass)
#define KB 128   // codes per k-chunk
#define DB 32    // d per LDS tile
#define TAU 1.0e-3f
#define RR 8     // rows per block (refine pass)

// workspace layout (bytes)
#define WS_COUNTER 0
#define WS_ESQ     16
#define WS_IDX     (WS_ESQ + K_CB*4)
#define WS_FLAG    (WS_IDX + N_ROWS*4)
#define WS_PART    (WS_FLAG + N_ROWS*4)
#define NUM_OUT_BLOCKS ((N_ROWS*(D_DIM/4))/256)   // 16384

// ---------- numpy-emulated sum of squares (pairwise, contraction OFF) ----------
// numpy pairwise_sum for n=128: 8 accumulators unrolled, combine
// ((r0+r1)+(r2+r3))+((r4+r5)+(r6+r7)). Squares are rounded separately (z**2
// is an elementwise op, NOT fused into the add).
__device__ __forceinline__ float np_sum128_sq(const float* p) {
#pragma clang fp contract(off)
  float r0 = p[0]*p[0], r1 = p[1]*p[1], r2 = p[2]*p[2], r3 = p[3]*p[3];
  float r4 = p[4]*p[4], r5 = p[5]*p[5], r6 = p[6]*p[6], r7 = p[7]*p[7];
  for (int i = 8; i < 128; i += 8) {
    r0 += p[i+0]*p[i+0]; r1 += p[i+1]*p[i+1];
    r2 += p[i+2]*p[i+2]; r3 += p[i+3]*p[i+3];
    r4 += p[i+4]*p[i+4]; r5 += p[i+5]*p[i+5];
    r6 += p[i+6]*p[i+6]; r7 += p[i+7]*p[i+7];
  }
  return ((r0+r1)+(r2+r3))+((r4+r5)+(r6+r7));
}
// n=256 > PW_BLOCKSIZE(128): split into 128+128, add the two partial sums.
__device__ __forceinline__ float np_sumsq256(const float* p) {
#pragma clang fp contract(off)
  float a = np_sum128_sq(p);
  float b = np_sum128_sq(p + 128);
  return a + b;
}

// ---------------- e_sq with numpy-exact rounding ----------------
__global__ __launch_bounds__(256) void esq_np_kernel(const float* __restrict__ cb,
                                                     float* __restrict__ esq) {
  const int k = blockIdx.x * 256 + threadIdx.x;
  esq[k] = np_sumsq256(cb + (size_t)k * D_DIM);
}

// ---------------- main fp32 argmin pass (fast, reassociated) ----------------
__global__ __launch_bounds__(256, 2) void argmin_kernel(
    const float4* __restrict__ z4, const float4* __restrict__ cb4,
    const float* __restrict__ esq, int* __restrict__ idx_out,
    int* __restrict__ flag, unsigned int* __restrict__ counter) {
  __shared__ float zt[DB][RB];
  __shared__ float et[DB][KB];
  const int t  = threadIdx.x;
  const int tr = t >> 4;
  const int tc = t & 15;
  const int row0 = blockIdx.x * RB;

  float min1[8], min2[8]; int idx1[8];
  #pragma unroll
  for (int i = 0; i < 8; ++i) { min1[i] = FLT_MAX; min2[i] = FLT_MAX; idx1[i] = 0; }

  for (int kc = 0; kc < K_CB / KB; ++kc) {
    const int k0 = kc * KB;
    float acc[8][8];
    #pragma unroll
    for (int i = 0; i < 8; ++i)
      #pragma unroll
      for (int j = 0; j < 8; ++j) acc[i][j] = 0.0f;

    float esqv[8];
    #pragma unroll
    for (int j = 0; j < 8; ++j) esqv[j] = esq[k0 + tc*8 + j];

    for (int dt = 0; dt < D_DIM / DB; ++dt) {
      __syncthreads();
      #pragma unroll
      for (int m = 0; m < 4; ++m) {
        int u  = t + 256*m;
        int dq = u & 7;
        int r  = u >> 3;
        float4 v = z4[(size_t)(row0 + r)*(D_DIM/4) + dt*8 + dq];
        zt[dq*4+0][r] = v.x; zt[dq*4+1][r] = v.y; zt[dq*4+2][r] = v.z; zt[dq*4+3][r] = v.w;
        float4 w = cb4[(size_t)(k0 + r)*(D_DIM/4) + dt*8 + dq];
        et[dq*4+0][r] = w.x; et[dq*4+1][r] = w.y; et[dq*4+2][r] = w.z; et[dq*4+3][r] = w.w;
      }
      __syncthreads();

      #pragma unroll 8
      for (int d = 0; d < DB; ++d) {
        float4 za = *(const float4*)&zt[d][tr*8];
        float4 zb = *(const float4*)&zt[d][tr*8+4];
        float4 ea = *(const float4*)&et[d][tc*8];
        float4 eb = *(const float4*)&et[d][tc*8+4];
        float zr[8] = {za.x, za.y, za.z, za.w, zb.x, zb.y, zb.z, zb.w};
        float ev[8] = {ea.x, ea.y, ea.z, ea.w, eb.x, eb.y, eb.z, eb.w};
        #pragma unroll
        for (int i = 0; i < 8; ++i)
          #pragma unroll
          for (int j = 0; j < 8; ++j)
            acc[i][j] += zr[i] * ev[j];
      }
    }

    #pragma unroll
    for (int j = 0; j < 8; ++j) {
      const int k = k0 + tc*8 + j;
      #pragma unroll
      for (int i = 0; i < 8; ++i) {
        float s = esqv[j] - 2.0f * acc[i][j];
        if (s < min1[i]) { min2[i] = min1[i]; min1[i] = s; idx1[i] = k; }
        else if (s < min2[i]) { min2[i] = s; }
      }
    }
  }

  #pragma unroll
  for (int i = 0; i < 8; ++i) {
    float m1 = min1[i], m2 = min2[i]; int id = idx1[i];
    #pragma unroll
    for (int off = 1; off < 16; off <<= 1) {
      float om1 = __shfl_xor(m1, off);
      float om2 = __shfl_xor(m2, off);
      int   oid = __shfl_xor(id, off);
      bool take = (om1 < m1) || (om1 == m1 && oid < id);
      float nm2 = take ? fminf(m1, om2) : fminf(m2, om1);
      if (take) { m1 = om1; id = oid; }
      m2 = nm2;
    }
    if (tc == 0) {
      int row = row0 + tr*8 + i;
      idx_out[row] = id;
      if (m2 - m1 < TAU) {
        unsigned int p = atomicAdd(counter, 1u);
        flag[p] = row;
      }
    }
  }
}

// ---------------- numpy-fp32-emulated re-score of ambiguous rows ----------------
// score(k) = fl( fl(zsq + esq[k]) - fl(2 * dot) ), dot = sequential-k fp32 FMA
// (BLAS microkernel order). argmin with first-index tie-break = np.argmin.
__global__ __launch_bounds__(256) void refine_np_kernel(
    const float* __restrict__ z, const float* __restrict__ cb,
    const float* __restrict__ esq, int* __restrict__ idx_out,
    const int* __restrict__ flag, const unsigned int* __restrict__ counter) {
  __shared__ float zrow[RR][D_DIM];
  __shared__ float zsq[RR];
  __shared__ float rbest[256];
  __shared__ int   rbidx[256];
  const int t = threadIdx.x;
  const unsigned int cnt = *counter;
  const unsigned int ngroups = (cnt + RR - 1) / RR;

  for (unsigned int g = blockIdx.x; g < ngroups; g += gridDim.x) {
    __syncthreads();
    const int nr = (int)min((unsigned int)RR, cnt - g*RR);
    #pragma unroll
    for (int r = 0; r < RR; ++r) {
      int fi = (int)(g*RR) + ((r < nr) ? r : 0);
      int row = flag[fi];
      zrow[r][t] = z[(size_t)row * D_DIM + t];
    }
    __syncthreads();
    if (t < RR) zsq[t] = np_sumsq256(&zrow[t][0]);
    __syncthreads();

    float best[RR]; int bidx[RR];
    #pragma unroll
    for (int r = 0; r < RR; ++r) { best[r] = FLT_MAX; bidx[r] = 0x7fffffff; }

    for (int m = 0; m < K_CB / 256; ++m) {
      const int k = m*256 + t;                    // ascending per thread
      const float4* e4 = (const float4*)(cb + (size_t)k * D_DIM);
      float acc[RR];
      #pragma unroll
      for (int r = 0; r < RR; ++r) acc[r] = 0.0f;
      for (int dq = 0; dq < D_DIM/4; ++dq) {
        float4 ev = e4[dq];
        #pragma unroll
        for (int r = 0; r < RR; ++r) {
          acc[r] = __fmaf_rn(zrow[r][dq*4+0], ev.x, acc[r]);
          acc[r] = __fmaf_rn(zrow[r][dq*4+1], ev.y, acc[r]);
          acc[r] = __fmaf_rn(zrow[r][dq*4+2], ev.z, acc[r]);
          acc[r] = __fmaf_rn(zrow[r][dq*4+3], ev.w, acc[r]);
        }
      }
      const float ek = esq[k];
      #pragma unroll
      for (int r = 0; r < RR; ++r) {
#pragma clang fp contract(off)
        float t1 = zsq[r] + ek;            // fl(zsq + esq)
        float t2 = 2.0f * acc[r];          // exact
        float sc = t1 - t2;                // fl(... - ...)
        if (sc < best[r]) { best[r] = sc; bidx[r] = k; }
      }
    }

    for (int r = 0; r < RR; ++r) {
      __syncthreads();
      rbest[t] = best[r]; rbidx[t] = bidx[r];
      __syncthreads();
      for (int off = 128; off > 0; off >>= 1) {
        if (t < off) {
          float ob = rbest[t+off]; int oi = rbidx[t+off];
          if (ob < rbest[t] || (ob == rbest[t] && oi < rbidx[t])) {
            rbest[t] = ob; rbidx[t] = oi;
          }
        }
        __syncthreads();
      }
      if (t == 0 && r < nr) idx_out[flag[g*RR + r]] = rbidx[0];
    }
  }
}

// ---------------- gather + outputs + loss partials ----------------
__global__ __launch_bounds__(256) void output_kernel(
    const float4* __restrict__ z4, const float4* __restrict__ cb4,
    const int* __restrict__ idx_out, float* __restrict__ out,
    double* __restrict__ partials) {
  const int g  = blockIdx.x * 256 + threadIdx.x;
  const int n  = g >> 6;
  const int dq = g & 63;
  const int id = idx_out[n];
  float4 q  = cb4[(size_t)id * (D_DIM/4) + dq];
  float4 zv = z4[(size_t)n  * (D_DIM/4) + dq];
  float dx = q.x - zv.x, dy = q.y - zv.y, dz = q.z - zv.z, dw = q.w - zv.w;
  double psum = (double)dx*dx + (double)dy*dy + (double)dz*dz + (double)dw*dw;
  size_t base = 1 + (size_t)n * D_DIM + (size_t)dq * 4;
  out[base+0] = q.x; out[base+1] = q.y; out[base+2] = q.z; out[base+3] = q.w;
  if (dq == 0) out[1 + (size_t)N_ROWS*D_DIM + n] = (float)id;

  __shared__ double sred[256];
  sred[threadIdx.x] = psum;
  __syncthreads();
  for (int off = 128; off > 0; off >>= 1) {
    if (threadIdx.x < off) sred[threadIdx.x] += sred[threadIdx.x + off];
    __syncthreads();
  }
  if (threadIdx.x == 0) partials[blockIdx.x] = sred[0];
}

__global__ __launch_bounds__(256) void loss_kernel(const double* __restrict__ partials,
                                                   float* __restrict__ out) {
  const int t = threadIdx.x;
  double s = 0.0;
  for (int m = 0; m < NUM_OUT_BLOCKS/256; ++m) s += partials[t + 256*m];
  __shared__ double sred[256];
  sred[t] = s;
  __syncthreads();
  for (int off = 128; off > 0; off >>= 1) {
    if (t < off) sred[t] += sred[t + off];
    __syncthreads();
  }
  if (t == 0) out[0] = (float)(1.25 * sred[0] / ((double)N_ROWS * (double)D_DIM));
}

extern "C" void kernel_launch(void* const* d_in, const int* in_sizes, int n_in,
                              void* d_out, int out_size, void* d_ws, size_t ws_size,
                              hipStream_t stream) {
  const float* z  = (const float*)d_in[0];
  const float* cb = (const float*)d_in[1];
  float* out = (float*)d_out;
  char* ws = (char*)d_ws;

  unsigned int* counter = (unsigned int*)(ws + WS_COUNTER);
  float*  esq     = (float*) (ws + WS_ESQ);
  int*    idx     = (int*)   (ws + WS_IDX);
  int*    flag    = (int*)   (ws + WS_FLAG);
  double* partials= (double*)(ws + WS_PART);

  hipMemsetAsync(ws, 0, 16, stream);
  esq_np_kernel<<<K_CB/256, 256, 0, stream>>>(cb, esq);
  argmin_kernel<<<N_ROWS/RB, 256, 0, stream>>>((const float4*)z, (const float4*)cb,
                                               esq, idx, flag, counter);
  refine_np_kernel<<<256, 256, 0, stream>>>(z, cb, esq, idx, flag, counter);
  output_kernel<<<NUM_OUT_BLOCKS, 256, 0, stream>>>((const float4*)z, (const float4*)cb,
                                                    idx, out, partials);
  loss_kernel<<<1, 256, 0, stream>>>(partials, out);
}

// Round 3
// 760.447 us; speedup vs baseline: 2.8588x; 2.8588x over previous
//
#include <hip/hip_runtime.h>
#include <float.h>

typedef __attribute__((ext_vector_type(8))) short short8;
typedef __attribute__((ext_vector_type(4))) float f32x4;

#define N_ROWS 65536
#define K_CB   4096
#define D_DIM  256
#define TAU    1.0e-3f
#define RR     8

// old-path tile params
#define RB 128
#define KB 128
#define DB 32

// workspace layout (bytes)
#define WS_COUNTER 0
#define WS_ESQ     16
#define WS_IDX     (WS_ESQ + K_CB*4)
#define WS_FLAG    (WS_IDX + N_ROWS*4)
#define WS_PART    (WS_FLAG + N_ROWS*4)
#define NUM_OUT_BLOCKS ((N_ROWS*(D_DIM/4))/256)   // 16384
#define WS_EH      (WS_PART + NUM_OUT_BLOCKS*8)
#define WS_EL      (WS_EH + K_CB*D_DIM*2)
#define WS_NEEDED  (WS_EL + (size_t)K_CB*D_DIM*2)

// ---------- bf16 split helpers (RNE, data has no NaN/Inf) ----------
__device__ __forceinline__ unsigned short f2bf(float x) {
  unsigned int u = __float_as_uint(x);
  unsigned int r = (u + 0x7fffu + ((u >> 16) & 1u)) >> 16;
  return (unsigned short)r;
}
__device__ __forceinline__ float bf2f(unsigned short b) {
  return __uint_as_float((unsigned int)b << 16);
}

// ---------- numpy-emulated pairwise sum of squares ----------
__device__ __forceinline__ float np_sum128_sq(const float* p) {
#pragma clang fp contract(off)
  float r0 = p[0]*p[0], r1 = p[1]*p[1], r2 = p[2]*p[2], r3 = p[3]*p[3];
  float r4 = p[4]*p[4], r5 = p[5]*p[5], r6 = p[6]*p[6], r7 = p[7]*p[7];
  for (int i = 8; i < 128; i += 8) {
    r0 += p[i+0]*p[i+0]; r1 += p[i+1]*p[i+1];
    r2 += p[i+2]*p[i+2]; r3 += p[i+3]*p[i+3];
    r4 += p[i+4]*p[i+4]; r5 += p[i+5]*p[i+5];
    r6 += p[i+6]*p[i+6]; r7 += p[i+7]*p[i+7];
  }
  return ((r0+r1)+(r2+r3))+((r4+r5)+(r6+r7));
}
__device__ __forceinline__ float np_sumsq256(const float* p) {
#pragma clang fp contract(off)
  float a = np_sum128_sq(p);
  float b = np_sum128_sq(p + 128);
  return a + b;
}

__global__ __launch_bounds__(256) void esq_np_kernel(const float* __restrict__ cb,
                                                     float* __restrict__ esq) {
  const int k = blockIdx.x * 256 + threadIdx.x;
  esq[k] = np_sumsq256(cb + (size_t)k * D_DIM);
}

// ---------- split precompute ----------
__global__ __launch_bounds__(256) void zsplit_kernel(const float4* __restrict__ z4,
                                                     unsigned short* __restrict__ zh,
                                                     unsigned short* __restrict__ zl) {
  const size_t i = (size_t)blockIdx.x * 256 + threadIdx.x;   // over N*D/4
  float4 v = z4[i];
  ushort4 h, lo;
  h.x = f2bf(v.x); lo.x = f2bf(v.x - bf2f(h.x));
  h.y = f2bf(v.y); lo.y = f2bf(v.y - bf2f(h.y));
  h.z = f2bf(v.z); lo.z = f2bf(v.z - bf2f(h.z));
  h.w = f2bf(v.w); lo.w = f2bf(v.w - bf2f(h.w));
  *(ushort4*)(zh + i*4) = h;
  *(ushort4*)(zl + i*4) = lo;
}

__global__ __launch_bounds__(256) void esplit_kernel(const float4* __restrict__ e4,
                                                     unsigned short* __restrict__ eh,
                                                     unsigned short* __restrict__ el) {
  const size_t i = (size_t)blockIdx.x * 256 + threadIdx.x;   // over K*D/4
  float4 v = e4[i];
  ushort4 h, lo;
  h.x = f2bf(v.x); lo.x = f2bf(v.x - bf2f(h.x));
  h.y = f2bf(v.y); lo.y = f2bf(v.y - bf2f(h.y));
  h.z = f2bf(v.z); lo.z = f2bf(v.z - bf2f(h.z));
  h.w = f2bf(v.w); lo.w = f2bf(v.w - bf2f(h.w));
  *(ushort4*)(eh + i*4) = h;
  *(ushort4*)(el + i*4) = lo;
}

// ---------------- MFMA split-bf16 argmin ----------------
// 512 threads = 8 waves; wave owns 16 rows. Zh/Zl fragments persistent in
// registers. Codebook chunks (64 codes x 64 d, hi+lo) double-buffered in
// XOR-swizzled LDS. acc per chunk -> fused top-2 epilogue.
__global__ __launch_bounds__(512) void mfma_argmin_kernel(
    const unsigned short* __restrict__ zh, const unsigned short* __restrict__ zl,
    const unsigned short* __restrict__ eh, const unsigned short* __restrict__ el,
    const float* __restrict__ esq, int* __restrict__ idx_out,
    int* __restrict__ flag, unsigned int* __restrict__ counter) {
  __shared__ char smem[2 * 16384];    // [buf][hi 8KB | lo 8KB]
  const int t  = threadIdx.x;
  const int w  = t >> 6;
  const int l  = t & 63;
  const int c  = l & 15;       // A-row / B-col lane index
  const int kg = l >> 4;       // k-group
  const int row0 = blockIdx.x * 128;
  const int swz = (c & 7) << 4;

  // persistent A fragments: rows row0 + w*16 + c, 8 k-steps of 32
  short8 ah[8], al[8];
  {
    const unsigned short* za = zh + ((size_t)(row0 + w*16 + c)) * D_DIM + kg*8;
    const unsigned short* zb = zl + ((size_t)(row0 + w*16 + c)) * D_DIM + kg*8;
    #pragma unroll
    for (int s = 0; s < 8; ++s) {
      ah[s] = *(const short8*)(za + s*32);
      al[s] = *(const short8*)(zb + s*32);
    }
  }

  // staging map: thread -> (code, 16B-unit)
  const int scode = t >> 3;
  const int su    = t & 7;
  const int woff  = scode*128 + ((su*16) ^ ((scode & 7) << 4));
  const size_t sgl = (size_t)scode * D_DIM + su*8;   // element offset within chunk base

  // prologue: stage phase 0 (kc=0, dp=0)
  {
    uint4 h  = *(const uint4*)(eh + sgl);
    uint4 lo = *(const uint4*)(el + sgl);
    *(uint4*)(smem + woff)        = h;
    *(uint4*)(smem + 8192 + woff) = lo;
  }
  __syncthreads();

  f32x4 acc[4];
  #pragma unroll
  for (int n = 0; n < 4; ++n) acc[n] = (f32x4){0.f, 0.f, 0.f, 0.f};
  float t1v[4], t2v[4]; int tiv[4];
  #pragma unroll
  for (int r = 0; r < 4; ++r) { t1v[r] = FLT_MAX; t2v[r] = FLT_MAX; tiv[r] = 0; }

  int cur = 0;
  const int cbase = c * 128;

  for (int pp = 0; pp < 64; ++pp) {          // chunk loop (64 codes each)
    #pragma unroll
    for (int q = 0; q < 4; ++q) {            // d-phase (64 d each), compile-time
      const int p = pp*4 + q;
      const bool hn = (p + 1 < 256);
      uint4 nh, nl;
      if (hn) {
        const int pn = p + 1, kcn = pn >> 2, dpn = pn & 3;
        const unsigned short* sh = eh + ((size_t)kcn*64)*D_DIM + dpn*64 + sgl;
        const unsigned short* sl = el + ((size_t)kcn*64)*D_DIM + dpn*64 + sgl;
        nh = *(const uint4*)sh;
        nl = *(const uint4*)sl;
      }
      const char* bb = smem + cur*16384;
      #pragma unroll
      for (int s = 0; s < 2; ++s) {
        const int sg = q*2 + s;              // compile-time
        const int koff = (s*64 + kg*16) ^ swz;
        #pragma unroll
        for (int n = 0; n < 4; ++n) {
          const int off = n*2048 + cbase + koff;
          short8 bh = *(const short8*)(bb + off);
          short8 bl = *(const short8*)(bb + 8192 + off);
          acc[n] = __builtin_amdgcn_mfma_f32_16x16x32_bf16(ah[sg], bh, acc[n], 0, 0, 0);
          acc[n] = __builtin_amdgcn_mfma_f32_16x16x32_bf16(ah[sg], bl, acc[n], 0, 0, 0);
          acc[n] = __builtin_amdgcn_mfma_f32_16x16x32_bf16(al[sg], bh, acc[n], 0, 0, 0);
        }
      }
      if (q == 3) {
        // chunk epilogue: scores + top-2 (codes ascending => first-index ties)
        #pragma unroll
        for (int n = 0; n < 4; ++n) {
          const int code = pp*64 + n*16 + c;
          const float ev = esq[code];
          #pragma unroll
          for (int r = 0; r < 4; ++r) {
            float s = fmaf(-2.0f, acc[n][r], ev);
            if (s < t1v[r]) { t2v[r] = t1v[r]; t1v[r] = s; tiv[r] = code; }
            else if (s < t2v[r]) { t2v[r] = s; }
          }
          acc[n] = (f32x4){0.f, 0.f, 0.f, 0.f};
        }
      }
      if (hn) {
        char* wb = smem + (cur ^ 1)*16384;
        *(uint4*)(wb + woff)        = nh;
        *(uint4*)(wb + 8192 + woff) = nl;
      }
      __syncthreads();
      cur ^= 1;
    }
  }

  // merge top-2 across the 16 c-lanes; lane c==0 holds rows kg*4 + r
  #pragma unroll
  for (int r = 0; r < 4; ++r) {
    float m1 = t1v[r], m2 = t2v[r]; int id = tiv[r];
    #pragma unroll
    for (int off = 1; off < 16; off <<= 1) {
      float om1 = __shfl_xor(m1, off);
      float om2 = __shfl_xor(m2, off);
      int   oid = __shfl_xor(id, off);
      bool take = (om1 < m1) || (om1 == m1 && oid < id);
      float nm2 = take ? fminf(m1, om2) : fminf(m2, om1);
      if (take) { m1 = om1; id = oid; }
      m2 = nm2;
    }
    if (c == 0) {
      const int row = row0 + w*16 + kg*4 + r;
      idx_out[row] = id;
      if (m2 - m1 < TAU) {
        unsigned int p = atomicAdd(counter, 1u);
        flag[p] = row;
      }
    }
  }
}

// ---------------- old fp32 argmin pass (fallback if ws too small) ----------------
__global__ __launch_bounds__(256, 2) void argmin_kernel(
    const float4* __restrict__ z4, const float4* __restrict__ cb4,
    const float* __restrict__ esq, int* __restrict__ idx_out,
    int* __restrict__ flag, unsigned int* __restrict__ counter) {
  __shared__ float zt[DB][RB];
  __shared__ float et[DB][KB];
  const int t  = threadIdx.x;
  const int tr = t >> 4;
  const int tc = t & 15;
  const int row0 = blockIdx.x * RB;

  float min1[8], min2[8]; int idx1[8];
  #pragma unroll
  for (int i = 0; i < 8; ++i) { min1[i] = FLT_MAX; min2[i] = FLT_MAX; idx1[i] = 0; }

  for (int kc = 0; kc < K_CB / KB; ++kc) {
    const int k0 = kc * KB;
    float acc[8][8];
    #pragma unroll
    for (int i = 0; i < 8; ++i)
      #pragma unroll
      for (int j = 0; j < 8; ++j) acc[i][j] = 0.0f;

    float esqv[8];
    #pragma unroll
    for (int j = 0; j < 8; ++j) esqv[j] = esq[k0 + tc*8 + j];

    for (int dt = 0; dt < D_DIM / DB; ++dt) {
      __syncthreads();
      #pragma unroll
      for (int m = 0; m < 4; ++m) {
        int u  = t + 256*m;
        int dq = u & 7;
        int r  = u >> 3;
        float4 v = z4[(size_t)(row0 + r)*(D_DIM/4) + dt*8 + dq];
        zt[dq*4+0][r] = v.x; zt[dq*4+1][r] = v.y; zt[dq*4+2][r] = v.z; zt[dq*4+3][r] = v.w;
        float4 wv = cb4[(size_t)(k0 + r)*(D_DIM/4) + dt*8 + dq];
        et[dq*4+0][r] = wv.x; et[dq*4+1][r] = wv.y; et[dq*4+2][r] = wv.z; et[dq*4+3][r] = wv.w;
      }
      __syncthreads();

      #pragma unroll 8
      for (int d = 0; d < DB; ++d) {
        float4 za = *(const float4*)&zt[d][tr*8];
        float4 zb = *(const float4*)&zt[d][tr*8+4];
        float4 ea = *(const float4*)&et[d][tc*8];
        float4 eb = *(const float4*)&et[d][tc*8+4];
        float zr[8] = {za.x, za.y, za.z, za.w, zb.x, zb.y, zb.z, zb.w};
        float ev[8] = {ea.x, ea.y, ea.z, ea.w, eb.x, eb.y, eb.z, eb.w};
        #pragma unroll
        for (int i = 0; i < 8; ++i)
          #pragma unroll
          for (int j = 0; j < 8; ++j)
            acc[i][j] += zr[i] * ev[j];
      }
    }

    #pragma unroll
    for (int j = 0; j < 8; ++j) {
      const int k = k0 + tc*8 + j;
      #pragma unroll
      for (int i = 0; i < 8; ++i) {
        float s = esqv[j] - 2.0f * acc[i][j];
        if (s < min1[i]) { min2[i] = min1[i]; min1[i] = s; idx1[i] = k; }
        else if (s < min2[i]) { min2[i] = s; }
      }
    }
  }

  #pragma unroll
  for (int i = 0; i < 8; ++i) {
    float m1 = min1[i], m2 = min2[i]; int id = idx1[i];
    #pragma unroll
    for (int off = 1; off < 16; off <<= 1) {
      float om1 = __shfl_xor(m1, off);
      float om2 = __shfl_xor(m2, off);
      int   oid = __shfl_xor(id, off);
      bool take = (om1 < m1) || (om1 == m1 && oid < id);
      float nm2 = take ? fminf(m1, om2) : fminf(m2, om1);
      if (take) { m1 = om1; id = oid; }
      m2 = nm2;
    }
    if (tc == 0) {
      int row = row0 + tr*8 + i;
      idx_out[row] = id;
      if (m2 - m1 < TAU) {
        unsigned int p = atomicAdd(counter, 1u);
        flag[p] = row;
      }
    }
  }
}

// ---------------- numpy-fp32-emulated re-score of ambiguous rows ----------------
__global__ __launch_bounds__(256) void refine_np_kernel(
    const float* __restrict__ z, const float* __restrict__ cb,
    const float* __restrict__ esq, int* __restrict__ idx_out,
    const int* __restrict__ flag, const unsigned int* __restrict__ counter) {
  __shared__ float zrow[RR][D_DIM];
  __shared__ float zsq[RR];
  __shared__ float rbest[256];
  __shared__ int   rbidx[256];
  const int t = threadIdx.x;
  const unsigned int cnt = *counter;
  const unsigned int ngroups = (cnt + RR - 1) / RR;

  for (unsigned int g = blockIdx.x; g < ngroups; g += gridDim.x) {
    __syncthreads();
    const int nr = (int)min((unsigned int)RR, cnt - g*RR);
    #pragma unroll
    for (int r = 0; r < RR; ++r) {
      int fi = (int)(g*RR) + ((r < nr) ? r : 0);
      int row = flag[fi];
      zrow[r][t] = z[(size_t)row * D_DIM + t];
    }
    __syncthreads();
    if (t < RR) zsq[t] = np_sumsq256(&zrow[t][0]);
    __syncthreads();

    float best[RR]; int bidx[RR];
    #pragma unroll
    for (int r = 0; r < RR; ++r) { best[r] = FLT_MAX; bidx[r] = 0x7fffffff; }

    for (int m = 0; m < K_CB / 256; ++m) {
      const int k = m*256 + t;
      const float4* e4 = (const float4*)(cb + (size_t)k * D_DIM);
      float acc[RR];
      #pragma unroll
      for (int r = 0; r < RR; ++r) acc[r] = 0.0f;
      for (int dq = 0; dq < D_DIM/4; ++dq) {
        float4 ev = e4[dq];
        #pragma unroll
        for (int r = 0; r < RR; ++r) {
          acc[r] = __fmaf_rn(zrow[r][dq*4+0], ev.x, acc[r]);
          acc[r] = __fmaf_rn(zrow[r][dq*4+1], ev.y, acc[r]);
          acc[r] = __fmaf_rn(zrow[r][dq*4+2], ev.z, acc[r]);
          acc[r] = __fmaf_rn(zrow[r][dq*4+3], ev.w, acc[r]);
        }
      }
      const float ek = esq[k];
      #pragma unroll
      for (int r = 0; r < RR; ++r) {
#pragma clang fp contract(off)
        float u1 = zsq[r] + ek;
        float u2 = 2.0f * acc[r];
        float sc = u1 - u2;
        if (sc < best[r]) { best[r] = sc; bidx[r] = k; }
      }
    }

    for (int r = 0; r < RR; ++r) {
      __syncthreads();
      rbest[t] = best[r]; rbidx[t] = bidx[r];
      __syncthreads();
      for (int off = 128; off > 0; off >>= 1) {
        if (t < off) {
          float ob = rbest[t+off]; int oi = rbidx[t+off];
          if (ob < rbest[t] || (ob == rbest[t] && oi < rbidx[t])) {
            rbest[t] = ob; rbidx[t] = oi;
          }
        }
        __syncthreads();
      }
      if (t == 0 && r < nr) idx_out[flag[g*RR + r]] = rbidx[0];
    }
  }
}

// ---------------- gather + outputs + loss partials ----------------
__global__ __launch_bounds__(256) void output_kernel(
    const float4* __restrict__ z4, const float4* __restrict__ cb4,
    const int* __restrict__ idx_out, float* __restrict__ out,
    double* __restrict__ partials) {
  const int g  = blockIdx.x * 256 + threadIdx.x;
  const int n  = g >> 6;
  const int dq = g & 63;
  const int id = idx_out[n];
  float4 q  = cb4[(size_t)id * (D_DIM/4) + dq];
  float4 zv = z4[(size_t)n  * (D_DIM/4) + dq];
  float dx = q.x - zv.x, dy = q.y - zv.y, dz = q.z - zv.z, dw = q.w - zv.w;
  double psum = (double)dx*dx + (double)dy*dy + (double)dz*dz + (double)dw*dw;
  size_t base = 1 + (size_t)n * D_DIM + (size_t)dq * 4;
  out[base+0] = q.x; out[base+1] = q.y; out[base+2] = q.z; out[base+3] = q.w;
  if (dq == 0) out[1 + (size_t)N_ROWS*D_DIM + n] = (float)id;

  __shared__ double sred[256];
  sred[threadIdx.x] = psum;
  __syncthreads();
  for (int off = 128; off > 0; off >>= 1) {
    if (threadIdx.x < off) sred[threadIdx.x] += sred[threadIdx.x + off];
    __syncthreads();
  }
  if (threadIdx.x == 0) partials[blockIdx.x] = sred[0];
}

__global__ __launch_bounds__(256) void loss_kernel(const double* __restrict__ partials,
                                                   float* __restrict__ out) {
  const int t = threadIdx.x;
  double s = 0.0;
  for (int m = 0; m < NUM_OUT_BLOCKS/256; ++m) s += partials[t + 256*m];
  __shared__ double sred[256];
  sred[t] = s;
  __syncthreads();
  for (int off = 128; off > 0; off >>= 1) {
    if (t < off) sred[t] += sred[t + off];
    __syncthreads();
  }
  if (t == 0) out[0] = (float)(1.25 * sred[0] / ((double)N_ROWS * (double)D_DIM));
}

extern "C" void kernel_launch(void* const* d_in, const int* in_sizes, int n_in,
                              void* d_out, int out_size, void* d_ws, size_t ws_size,
                              hipStream_t stream) {
  const float* z  = (const float*)d_in[0];
  const float* cb = (const float*)d_in[1];
  float* out = (float*)d_out;
  char* ws = (char*)d_ws;

  unsigned int* counter = (unsigned int*)(ws + WS_COUNTER);
  float*  esq      = (float*) (ws + WS_ESQ);
  int*    idx      = (int*)   (ws + WS_IDX);
  int*    flag     = (int*)   (ws + WS_FLAG);
  double* partials = (double*)(ws + WS_PART);

  hipMemsetAsync(ws, 0, 16, stream);
  esq_np_kernel<<<K_CB/256, 256, 0, stream>>>(cb, esq);

  if (ws_size >= WS_NEEDED) {
    // fast path: split-bf16 MFMA argmin.
    // zh/zl live in the d_out quantized region (overwritten by output_kernel later).
    unsigned short* zh = (unsigned short*)(out + 4);
    unsigned short* zl = zh + (size_t)N_ROWS * D_DIM;
    unsigned short* eh = (unsigned short*)(ws + WS_EH);
    unsigned short* el = (unsigned short*)(ws + WS_EL);

    zsplit_kernel<<<(N_ROWS*(D_DIM/4))/256, 256, 0, stream>>>((const float4*)z, zh, zl);
    esplit_kernel<<<(K_CB*(D_DIM/4))/256, 256, 0, stream>>>((const float4*)cb, eh, el);
    mfma_argmin_kernel<<<N_ROWS/128, 512, 0, stream>>>(zh, zl, eh, el, esq,
                                                       idx, flag, counter);
  } else {
    // fallback: fp32 vector-ALU argmin (R2 path)
    argmin_kernel<<<N_ROWS/RB, 256, 0, stream>>>((const float4*)z, (const float4*)cb,
                                                 esq, idx, flag, counter);
  }

  refine_np_kernel<<<256, 256, 0, stream>>>(z, cb, esq, idx, flag, counter);
  output_kernel<<<NUM_OUT_BLOCKS, 256, 0, stream>>>((const float4*)z, (const float4*)cb,
                                                    idx, out, partials);
  loss_kernel<<<1, 256, 0, stream>>>(partials, out);
}

// Round 4
// 570.620 us; speedup vs baseline: 3.8098x; 1.3327x over previous
//
#include <hip/hip_runtime.h>
#include <float.h>

typedef __attribute__((ext_vector_type(8))) short short8;
typedef __attribute__((ext_vector_type(16))) float f32x16;
typedef unsigned short u16;

#define N_ROWS 65536
#define K_CB   4096
#define D_DIM  256
#define TAU    1.0e-3f
#define RR     8

// old-path tile params (fallback)
#define RB 128
#define KB 128
#define DB 32

// workspace layout (bytes)
#define WS_COUNTER 0
#define WS_ESQ     16
#define WS_IDX     (WS_ESQ + K_CB*4)
#define WS_FLAG    (WS_IDX + N_ROWS*4)
#define WS_PART    (WS_FLAG + N_ROWS*4)
#define NUM_OUT_BLOCKS ((N_ROWS*(D_DIM/4))/256)   // 16384
#define WS_EH      (WS_PART + NUM_OUT_BLOCKS*8)
#define WS_EL      (WS_EH + K_CB*D_DIM*2)
#define WS_NEEDED  (WS_EL + (size_t)K_CB*D_DIM*2)

// ---------- bf16 split helpers (RNE) ----------
__device__ __forceinline__ u16 f2bf(float x) {
  unsigned int u = __float_as_uint(x);
  unsigned int r = (u + 0x7fffu + ((u >> 16) & 1u)) >> 16;
  return (u16)r;
}
__device__ __forceinline__ float bf2f(u16 b) {
  return __uint_as_float((unsigned int)b << 16);
}

// ---------- numpy-emulated pairwise sum of squares ----------
__device__ __forceinline__ float np_sum128_sq(const float* p) {
#pragma clang fp contract(off)
  float r0 = p[0]*p[0], r1 = p[1]*p[1], r2 = p[2]*p[2], r3 = p[3]*p[3];
  float r4 = p[4]*p[4], r5 = p[5]*p[5], r6 = p[6]*p[6], r7 = p[7]*p[7];
  for (int i = 8; i < 128; i += 8) {
    r0 += p[i+0]*p[i+0]; r1 += p[i+1]*p[i+1];
    r2 += p[i+2]*p[i+2]; r3 += p[i+3]*p[i+3];
    r4 += p[i+4]*p[i+4]; r5 += p[i+5]*p[i+5];
    r6 += p[i+6]*p[i+6]; r7 += p[i+7]*p[i+7];
  }
  return ((r0+r1)+(r2+r3))+((r4+r5)+(r6+r7));
}
__device__ __forceinline__ float np_sumsq256(const float* p) {
#pragma clang fp contract(off)
  float a = np_sum128_sq(p);
  float b = np_sum128_sq(p + 128);
  return a + b;
}

__global__ __launch_bounds__(256) void esq_np_kernel(const float* __restrict__ cb,
                                                     float* __restrict__ esq) {
  const int k = blockIdx.x * 256 + threadIdx.x;
  esq[k] = np_sumsq256(cb + (size_t)k * D_DIM);
}

// ---------- codebook split into MFMA-fragment-permuted bf16 hi/lo ----------
// Chunk kc = 32 codes. Element layout within chunk (8192 elems = 16 KB):
//   off = d8*256 + c*8 + j   (d8 = d>>3, c = code&31, j = d&7)
// so a B-frag ds_read for k-step s, lane l is a contiguous 16B at
//   s*1024 + (l>>5)*512 + (l&31)*16  bytes — conflict-free across the wave.
__global__ __launch_bounds__(256) void esplit_perm_kernel(const float* __restrict__ cb,
                                                          u16* __restrict__ ehp,
                                                          u16* __restrict__ elp) {
  const int g  = blockIdx.x * 256 + threadIdx.x;   // K*D/8 threads
  const int k  = g >> 5;
  const int d8 = g & 31;
  const int kc = k >> 5, c = k & 31;
  const float* src = cb + (size_t)k * D_DIM + d8 * 8;
  float4 f0 = *(const float4*)src;
  float4 f1 = *(const float4*)(src + 4);
  float f[8] = {f0.x, f0.y, f0.z, f0.w, f1.x, f1.y, f1.z, f1.w};
  short8 h, lo;
  #pragma unroll
  for (int j = 0; j < 8; ++j) {
    u16 hb = f2bf(f[j]);
    h[j]  = (short)hb;
    lo[j] = (short)f2bf(f[j] - bf2f(hb));
  }
  const size_t off = (size_t)kc * 8192 + (size_t)d8 * 256 + (size_t)c * 8;
  *(short8*)(ehp + off) = h;
  *(short8*)(elp + off) = lo;
}

// ---------------- 32x32x16 split-bf16 MFMA argmin ----------------
// 256 thr = 4 waves; wave owns 32 rows (A hi/lo persistent in 128 VGPRs).
// B chunks (32 codes x 256 d, hi+lo = 32 KB) double-buffered in LDS,
// reg-staged with early-issue loads. One barrier per chunk. Branchless top-2.
__global__ __launch_bounds__(256, 2) void mfma_argmin32_kernel(
    const float* __restrict__ z, const u16* __restrict__ ehp,
    const u16* __restrict__ elp, const float* __restrict__ esq,
    int* __restrict__ idx_out, int* __restrict__ flag,
    unsigned int* __restrict__ counter) {
  __shared__ u16 smem[2 * 16384];   // 64 KB
  const int t   = threadIdx.x;
  const int w   = t >> 6;
  const int l   = t & 63;
  const int col = l & 31;
  const int hi  = l >> 5;
  const int row = blockIdx.x * 128 + w * 32 + col;

  // A fragments: z row split to bf16 hi/lo, 16 k-steps of 16
  short8 ah[16], al[16];
  {
    const float* zr = z + (size_t)row * D_DIM + hi * 8;
    #pragma unroll
    for (int s = 0; s < 16; ++s) {
      float4 f0 = *(const float4*)(zr + s * 16);
      float4 f1 = *(const float4*)(zr + s * 16 + 4);
      float f[8] = {f0.x, f0.y, f0.z, f0.w, f1.x, f1.y, f1.z, f1.w};
      short8 h, lo;
      #pragma unroll
      for (int j = 0; j < 8; ++j) {
        u16 hb = f2bf(f[j]);
        h[j]  = (short)hb;
        lo[j] = (short)f2bf(f[j] - bf2f(hb));
      }
      ah[s] = h; al[s] = lo;
    }
  }

  float m1[16], m2[16]; int ic[16];
  #pragma unroll
  for (int r = 0; r < 16; ++r) { m1[r] = FLT_MAX; m2[r] = FLT_MAX; ic[r] = 0; }

  uint4 stg[8];
  // prologue: stage chunk 0 into buf 0
  {
    #pragma unroll
    for (int q = 0; q < 4; ++q) {
      stg[q]     = *(const uint4*)(ehp + q * 2048 + t * 8);
      stg[4 + q] = *(const uint4*)(elp + q * 2048 + t * 8);
    }
    char* b = (char*)smem;
    #pragma unroll
    for (int q = 0; q < 4; ++q) {
      *(uint4*)(b + q * 4096 + t * 16)         = stg[q];
      *(uint4*)(b + 16384 + q * 4096 + t * 16) = stg[4 + q];
    }
  }
  __syncthreads();

  const int boff = hi * 512 + col * 16;
  for (int kc = 0; kc < 128; ++kc) {
    const int cur = kc & 1;
    if (kc + 1 < 128) {           // T14: issue next-chunk loads early
      const u16* s0 = ehp + (size_t)(kc + 1) * 8192;
      const u16* s1 = elp + (size_t)(kc + 1) * 8192;
      #pragma unroll
      for (int q = 0; q < 4; ++q) {
        stg[q]     = *(const uint4*)(s0 + q * 2048 + t * 8);
        stg[4 + q] = *(const uint4*)(s1 + q * 2048 + t * 8);
      }
    }
    const float ev = esq[kc * 32 + col];
    const char* bb = (const char*)smem + cur * 32768;
    f32x16 acc = {};
    #pragma unroll
    for (int s = 0; s < 16; ++s) {
      short8 bh = *(const short8*)(bb + s * 1024 + boff);
      short8 bl = *(const short8*)(bb + 16384 + s * 1024 + boff);
      acc = __builtin_amdgcn_mfma_f32_32x32x16_bf16(ah[s], bh, acc, 0, 0, 0);
      acc = __builtin_amdgcn_mfma_f32_32x32x16_bf16(al[s], bh, acc, 0, 0, 0);
      acc = __builtin_amdgcn_mfma_f32_32x32x16_bf16(ah[s], bl, acc, 0, 0, 0);
    }
    // branchless top-2 (kc ascending -> first-index tie-break within lane)
    #pragma unroll
    for (int r = 0; r < 16; ++r) {
      float sc = fmaf(-2.0f, acc[r], ev);
      bool lt = sc < m1[r];
      ic[r] = lt ? kc : ic[r];
      m2[r] = fminf(m2[r], fmaxf(m1[r], sc));
      m1[r] = fminf(m1[r], sc);
    }
    if (kc + 1 < 128) {           // write-late into the other buffer
      char* b = (char*)smem + (cur ^ 1) * 32768;
      #pragma unroll
      for (int q = 0; q < 4; ++q) {
        *(uint4*)(b + q * 4096 + t * 16)         = stg[q];
        *(uint4*)(b + 16384 + q * 4096 + t * 16) = stg[4 + q];
      }
    }
    __syncthreads();
  }

  // merge top-2 across the 32 lanes of this half (codes of each chunk)
  #pragma unroll
  for (int r = 0; r < 16; ++r) {
    float a1 = m1[r], a2 = m2[r];
    int cd = ic[r] * 32 + col;
    #pragma unroll
    for (int off = 1; off < 32; off <<= 1) {
      float b1 = __shfl_xor(a1, off);
      float b2 = __shfl_xor(a2, off);
      int   bc = __shfl_xor(cd, off);
      bool take = (b1 < a1) || (b1 == a1 && bc < cd);
      float nm2 = take ? fminf(a1, b2) : fminf(a2, b1);
      if (take) { a1 = b1; cd = bc; }
      a2 = nm2;
    }
    if (col == 0) {
      const int orow = blockIdx.x * 128 + w * 32 + (r & 3) + 8 * (r >> 2) + 4 * hi;
      idx_out[orow] = cd;
      if (a2 - a1 < TAU) {
        unsigned int p = atomicAdd(counter, 1u);
        flag[p] = orow;
      }
    }
  }
}

// ---------------- fallback fp32 argmin (if ws too small) ----------------
__global__ __launch_bounds__(256, 2) void argmin_kernel(
    const float4* __restrict__ z4, const float4* __restrict__ cb4,
    const float* __restrict__ esq, int* __restrict__ idx_out,
    int* __restrict__ flag, unsigned int* __restrict__ counter) {
  __shared__ float zt[DB][RB];
  __shared__ float et[DB][KB];
  const int t  = threadIdx.x;
  const int tr = t >> 4;
  const int tc = t & 15;
  const int row0 = blockIdx.x * RB;

  float min1[8], min2[8]; int idx1[8];
  #pragma unroll
  for (int i = 0; i < 8; ++i) { min1[i] = FLT_MAX; min2[i] = FLT_MAX; idx1[i] = 0; }

  for (int kc = 0; kc < K_CB / KB; ++kc) {
    const int k0 = kc * KB;
    float acc[8][8];
    #pragma unroll
    for (int i = 0; i < 8; ++i)
      #pragma unroll
      for (int j = 0; j < 8; ++j) acc[i][j] = 0.0f;

    float esqv[8];
    #pragma unroll
    for (int j = 0; j < 8; ++j) esqv[j] = esq[k0 + tc*8 + j];

    for (int dt = 0; dt < D_DIM / DB; ++dt) {
      __syncthreads();
      #pragma unroll
      for (int m = 0; m < 4; ++m) {
        int u  = t + 256*m;
        int dq = u & 7;
        int r  = u >> 3;
        float4 v = z4[(size_t)(row0 + r)*(D_DIM/4) + dt*8 + dq];
        zt[dq*4+0][r] = v.x; zt[dq*4+1][r] = v.y; zt[dq*4+2][r] = v.z; zt[dq*4+3][r] = v.w;
        float4 wv = cb4[(size_t)(k0 + r)*(D_DIM/4) + dt*8 + dq];
        et[dq*4+0][r] = wv.x; et[dq*4+1][r] = wv.y; et[dq*4+2][r] = wv.z; et[dq*4+3][r] = wv.w;
      }
      __syncthreads();

      #pragma unroll 8
      for (int d = 0; d < DB; ++d) {
        float4 za = *(const float4*)&zt[d][tr*8];
        float4 zb = *(const float4*)&zt[d][tr*8+4];
        float4 ea = *(const float4*)&et[d][tc*8];
        float4 eb = *(const float4*)&et[d][tc*8+4];
        float zr[8] = {za.x, za.y, za.z, za.w, zb.x, zb.y, zb.z, zb.w};
        float ev[8] = {ea.x, ea.y, ea.z, ea.w, eb.x, eb.y, eb.z, eb.w};
        #pragma unroll
        for (int i = 0; i < 8; ++i)
          #pragma unroll
          for (int j = 0; j < 8; ++j)
            acc[i][j] += zr[i] * ev[j];
      }
    }

    #pragma unroll
    for (int j = 0; j < 8; ++j) {
      const int k = k0 + tc*8 + j;
      #pragma unroll
      for (int i = 0; i < 8; ++i) {
        float s = esqv[j] - 2.0f * acc[i][j];
        if (s < min1[i]) { min2[i] = min1[i]; min1[i] = s; idx1[i] = k; }
        else if (s < min2[i]) { min2[i] = s; }
      }
    }
  }

  #pragma unroll
  for (int i = 0; i < 8; ++i) {
    float m1 = min1[i], m2 = min2[i]; int id = idx1[i];
    #pragma unroll
    for (int off = 1; off < 16; off <<= 1) {
      float om1 = __shfl_xor(m1, off);
      float om2 = __shfl_xor(m2, off);
      int   oid = __shfl_xor(id, off);
      bool take = (om1 < m1) || (om1 == m1 && oid < id);
      float nm2 = take ? fminf(m1, om2) : fminf(m2, om1);
      if (take) { m1 = om1; id = oid; }
      m2 = nm2;
    }
    if (tc == 0) {
      int row = row0 + tr*8 + i;
      idx_out[row] = id;
      if (m2 - m1 < TAU) {
        unsigned int p = atomicAdd(counter, 1u);
        flag[p] = row;
      }
    }
  }
}

// ---------------- numpy-fp32-emulated re-score of ambiguous rows ----------------
__global__ __launch_bounds__(256) void refine_np_kernel(
    const float* __restrict__ z, const float* __restrict__ cb,
    const float* __restrict__ esq, int* __restrict__ idx_out,
    const int* __restrict__ flag, const unsigned int* __restrict__ counter) {
  __shared__ float zrow[RR][D_DIM];
  __shared__ float zsq[RR];
  __shared__ float rbest[256];
  __shared__ int   rbidx[256];
  const int t = threadIdx.x;
  const unsigned int cnt = *counter;
  const unsigned int ngroups = (cnt + RR - 1) / RR;

  for (unsigned int g = blockIdx.x; g < ngroups; g += gridDim.x) {
    __syncthreads();
    const int nr = (int)min((unsigned int)RR, cnt - g*RR);
    #pragma unroll
    for (int r = 0; r < RR; ++r) {
      int fi = (int)(g*RR) + ((r < nr) ? r : 0);
      int row = flag[fi];
      zrow[r][t] = z[(size_t)row * D_DIM + t];
    }
    __syncthreads();
    if (t < RR) zsq[t] = np_sumsq256(&zrow[t][0]);
    __syncthreads();

    float best[RR]; int bidx[RR];
    #pragma unroll
    for (int r = 0; r < RR; ++r) { best[r] = FLT_MAX; bidx[r] = 0x7fffffff; }

    for (int m = 0; m < K_CB / 256; ++m) {
      const int k = m*256 + t;
      const float4* e4 = (const float4*)(cb + (size_t)k * D_DIM);
      float acc[RR];
      #pragma unroll
      for (int r = 0; r < RR; ++r) acc[r] = 0.0f;
      for (int dq = 0; dq < D_DIM/4; ++dq) {
        float4 ev = e4[dq];
        #pragma unroll
        for (int r = 0; r < RR; ++r) {
          acc[r] = __fmaf_rn(zrow[r][dq*4+0], ev.x, acc[r]);
          acc[r] = __fmaf_rn(zrow[r][dq*4+1], ev.y, acc[r]);
          acc[r] = __fmaf_rn(zrow[r][dq*4+2], ev.z, acc[r]);
          acc[r] = __fmaf_rn(zrow[r][dq*4+3], ev.w, acc[r]);
        }
      }
      const float ek = esq[k];
      #pragma unroll
      for (int r = 0; r < RR; ++r) {
#pragma clang fp contract(off)
        float u1 = zsq[r] + ek;
        float u2 = 2.0f * acc[r];
        float sc = u1 - u2;
        if (sc < best[r]) { best[r] = sc; bidx[r] = k; }
      }
    }

    for (int r = 0; r < RR; ++r) {
      __syncthreads();
      rbest[t] = best[r]; rbidx[t] = bidx[r];
      __syncthreads();
      for (int off = 128; off > 0; off >>= 1) {
        if (t < off) {
          float ob = rbest[t+off]; int oi = rbidx[t+off];
          if (ob < rbest[t] || (ob == rbest[t] && oi < rbidx[t])) {
            rbest[t] = ob; rbidx[t] = oi;
          }
        }
        __syncthreads();
      }
      if (t == 0 && r < nr) idx_out[flag[g*RR + r]] = rbidx[0];
    }
  }
}

// ---------------- gather + outputs + loss partials ----------------
__global__ __launch_bounds__(256) void output_kernel(
    const float4* __restrict__ z4, const float4* __restrict__ cb4,
    const int* __restrict__ idx_out, float* __restrict__ out,
    double* __restrict__ partials) {
  const int g  = blockIdx.x * 256 + threadIdx.x;
  const int n  = g >> 6;
  const int dq = g & 63;
  const int id = idx_out[n];
  float4 q  = cb4[(size_t)id * (D_DIM/4) + dq];
  float4 zv = z4[(size_t)n  * (D_DIM/4) + dq];
  float dx = q.x - zv.x, dy = q.y - zv.y, dz = q.z - zv.z, dw = q.w - zv.w;
  double psum = (double)dx*dx + (double)dy*dy + (double)dz*dz + (double)dw*dw;
  size_t base = 1 + (size_t)n * D_DIM + (size_t)dq * 4;
  out[base+0] = q.x; out[base+1] = q.y; out[base+2] = q.z; out[base+3] = q.w;
  if (dq == 0) out[1 + (size_t)N_ROWS*D_DIM + n] = (float)id;

  __shared__ double sred[256];
  sred[threadIdx.x] = psum;
  __syncthreads();
  for (int off = 128; off > 0; off >>= 1) {
    if (threadIdx.x < off) sred[threadIdx.x] += sred[threadIdx.x + off];
    __syncthreads();
  }
  if (threadIdx.x == 0) partials[blockIdx.x] = sred[0];
}

__global__ __launch_bounds__(256) void loss_kernel(const double* __restrict__ partials,
                                                   float* __restrict__ out) {
  const int t = threadIdx.x;
  double s = 0.0;
  for (int m = 0; m < NUM_OUT_BLOCKS/256; ++m) s += partials[t + 256*m];
  __shared__ double sred[256];
  sred[t] = s;
  __syncthreads();
  for (int off = 128; off > 0; off >>= 1) {
    if (t < off) sred[t] += sred[t + off];
    __syncthreads();
  }
  if (t == 0) out[0] = (float)(1.25 * sred[0] / ((double)N_ROWS * (double)D_DIM));
}

extern "C" void kernel_launch(void* const* d_in, const int* in_sizes, int n_in,
                              void* d_out, int out_size, void* d_ws, size_t ws_size,
                              hipStream_t stream) {
  const float* z  = (const float*)d_in[0];
  const float* cb = (const float*)d_in[1];
  float* out = (float*)d_out;
  char* ws = (char*)d_ws;

  unsigned int* counter = (unsigned int*)(ws + WS_COUNTER);
  float*  esq      = (float*) (ws + WS_ESQ);
  int*    idx      = (int*)   (ws + WS_IDX);
  int*    flag     = (int*)   (ws + WS_FLAG);
  double* partials = (double*)(ws + WS_PART);

  hipMemsetAsync(ws, 0, 16, stream);
  esq_np_kernel<<<K_CB/256, 256, 0, stream>>>(cb, esq);

  if (ws_size >= WS_NEEDED) {
    u16* ehp = (u16*)(ws + WS_EH);
    u16* elp = (u16*)(ws + WS_EL);
    esplit_perm_kernel<<<(K_CB*(D_DIM/8))/256, 256, 0, stream>>>(cb, ehp, elp);
    mfma_argmin32_kernel<<<N_ROWS/128, 256, 0, stream>>>(z, ehp, elp, esq,
                                                         idx, flag, counter);
  } else {
    argmin_kernel<<<N_ROWS/RB, 256, 0, stream>>>((const float4*)z, (const float4*)cb,
                                                 esq, idx, flag, counter);
  }

  refine_np_kernel<<<256, 256, 0, stream>>>(z, cb, esq, idx, flag, counter);
  output_kernel<<<NUM_OUT_BLOCKS, 256, 0, stream>>>((const float4*)z, (const float4*)cb,
                                                    idx, out, partials);
  loss_kernel<<<1, 256, 0, stream>>>(partials, out);
}